// Round 14
// baseline (201.466 us; speedup 1.0000x reference)
//
#include <hip/hip_runtime.h>
#include <hip/hip_bf16.h>
#include <cstdint>
#include <cstddef>

#define TQ 2048
#define CDIM 1024
#define NH 16
#define HD 64

typedef __attribute__((ext_vector_type(8))) short bf16x8;
typedef __attribute__((ext_vector_type(4))) float f32x4;
typedef __attribute__((ext_vector_type(16))) float f32x16;

__device__ __forceinline__ unsigned short f2bf(float f) {
  union { float f; unsigned u; } x; x.f = f;
  unsigned r = x.u + 0x7fffu + ((x.u >> 16) & 1u);
  return (unsigned short)(r >> 16);
}

__device__ __forceinline__ unsigned cvtpk(float lo, float hi) {
  unsigned r;
  asm("v_cvt_pk_bf16_f32 %0, %1, %2" : "=v"(r) : "v"(lo), "v"(hi));
  return r;
}

__device__ __forceinline__ void plswap(unsigned& x, unsigned& y) {
  asm("v_permlane32_swap_b32 %0, %1" : "+v"(x), "+v"(y));
}

__device__ __forceinline__ float exp2_fast(float x) {
  float r;
  asm("v_exp_f32 %0, %1" : "=v"(r) : "v"(x));
  return r;
}

__device__ __forceinline__ void gload_lds16(const void* g, void* l) {
  typedef __attribute__((address_space(1))) const void gv;
  typedef __attribute__((address_space(3))) void lv;
  __builtin_amdgcn_global_load_lds((gv*)g, (lv*)l, 16, 0, 0);
}

#define BAR() do { asm volatile("" ::: "memory"); __builtin_amdgcn_s_barrier(); asm volatile("" ::: "memory"); } while (0)
#define VMC2() asm volatile("s_waitcnt vmcnt(2)" ::: "memory")
#define VMC0() asm volatile("s_waitcnt vmcnt(0)" ::: "memory")

// ---------------- fused fp32 -> bf16 converts (x + 4 weights, one dispatch) --------
__global__ void cvt_all_kernel(const float* __restrict__ x,
                               const float* __restrict__ w0, const float* __restrict__ w1,
                               const float* __restrict__ w2, const float* __restrict__ w3,
                               unsigned short* __restrict__ xb,
                               unsigned short* __restrict__ wb) {
  const int bid = (int)blockIdx.x;
  if (bid < 4096) {
    for (int i = bid * 256 + threadIdx.x; i < 2097152; i += 4096 * 256) {
      float4 v = *(const float4*)(x + (size_t)i * 4);
      ushort4 o;
      o.x = f2bf(v.x); o.y = f2bf(v.y); o.z = f2bf(v.z); o.w = f2bf(v.w);
      *(ushort4*)(xb + (size_t)i * 4) = o;
    }
  } else {
    int i = (bid - 4096) * 256 + threadIdx.x;
    int which = i >> 18;
    const float* src = which == 0 ? w0 : which == 1 ? w1 : which == 2 ? w2 : w3;
    int off = (i & 262143) * 4;
    float4 v = *(const float4*)(src + off);
    ushort4 o;
    o.x = f2bf(v.x); o.y = f2bf(v.y); o.z = f2bf(v.z); o.w = f2bf(v.w);
    *(ushort4*)(wb + (size_t)i * 4) = o;
  }
}

// ---------------- 256x256 8-phase GEMM — used for QK (row-major decode) -------------
// EPI 4: fused QK: n<1024 -> Q*0.125*log2e [B,H,T,D] (b0); else K at +8M elems (b1)
template <int EPI>
__global__ __launch_bounds__(512, 2) void gemm256_kernel(
    const unsigned short* __restrict__ A,
    const unsigned short* __restrict__ Bt,
    const float* __restrict__ b0, const float* __restrict__ b1,
    void* __restrict__ outp,
    int M, int N, int K) {
  __shared__ __align__(16) char lds[131072];

  const int tid = (int)threadIdx.x;
  const int w = tid >> 6, lane = tid & 63;
  const int g = lane >> 4, c = lane & 15;
  const int wm = w >> 2, wn = w & 3;

  const int nbm = M >> 8, nbn = N >> 8;
  const int nwg = nbm * nbn;
  int id = (int)blockIdx.x;
  const int cpx = nwg >> 3;
  id = (id & 7) * cpx + (id >> 3);
  const int tn = id % nbn, tm = id / nbn;

  const char* Ab = (const char*)(A + (size_t)tm * 256 * K);
  const char* Bb = (const char*)(Bt + (size_t)tn * 256 * K);
  const int rowB = K * 2;
  const int nht = (K >> 6) << 2;

  char* aw = lds + wm * 16384;
  char* bw = lds + 65536 + (wn >> 1) * 16384;
  const int bfo = (wn & 1) * 8;

  auto stage_ht = [&](int j) {
    if (j >= nht) return;
    const int t = j >> 2, part = j & 3;
    const int isB = part >> 1, half = part & 1;
    const char* src = isB ? Bb : Ab;
    char* dst = lds + isB * 65536 + (t & 1) * 32768 + half * 16384 + w * 2048;
#pragma unroll
    for (int r = 0; r < 2; ++r) {
      const int f = w * 2 + r;
      const int m16 = f >> 1, ki = f & 1;
      gload_lds16(src + (size_t)(half * 128 + m16 * 16 + c) * rowB +
                      t * 128 + ki * 64 + g * 16,
                  dst + r * 1024);
    }
  };

  f32x4 acc[8][4];
#pragma unroll
  for (int i = 0; i < 8; ++i)
#pragma unroll
    for (int j = 0; j < 4; ++j) acc[i][j] = (f32x4){0.f, 0.f, 0.f, 0.f};
  bf16x8 af[4][2], bv[2][2];

  auto rdA = [&](int buf, int ms) {
#pragma unroll
    for (int mi = 0; mi < 4; ++mi)
#pragma unroll
      for (int ki = 0; ki < 2; ++ki)
        af[mi][ki] = *(const bf16x8*)(aw + buf * 32768 +
                                      ((ms * 4 + mi) * 2 + ki) * 1024 + lane * 16);
  };
  auto rdB = [&](int buf, int ns) {
#pragma unroll
    for (int ni = 0; ni < 2; ++ni)
#pragma unroll
      for (int ki = 0; ki < 2; ++ki)
        bv[ni][ki] = *(const bf16x8*)(bw + buf * 32768 +
                                      (bfo + (ns * 2 + ni) * 2 + ki) * 1024 + lane * 16);
  };
  auto mm = [&](int ms, int ns) {
    __builtin_amdgcn_s_setprio(1);
#pragma unroll
    for (int mi = 0; mi < 4; ++mi)
#pragma unroll
      for (int ni = 0; ni < 2; ++ni)
#pragma unroll
        for (int ki = 0; ki < 2; ++ki)
          acc[ms * 4 + mi][ns * 2 + ni] = __builtin_amdgcn_mfma_f32_16x16x32_bf16(
              af[mi][ki], bv[ni][ki], acc[ms * 4 + mi][ns * 2 + ni], 0, 0, 0);
    __builtin_amdgcn_s_setprio(0);
  };

  for (int j = 0; j < 5; ++j) stage_ht(j);
  VMC2();
  BAR();

  const int niter = K >> 7;
#pragma unroll 1
  for (int i = 0; i < niter; ++i) {
    const int j0 = 5 + (i << 3);
    rdA(0, 0); rdB(0, 0); stage_ht(j0 + 0); BAR(); mm(0, 0); BAR();
    rdB(0, 1);            stage_ht(j0 + 1); BAR(); mm(0, 1); BAR();
    rdA(0, 1);            stage_ht(j0 + 2); BAR(); mm(1, 1); BAR();
    rdB(0, 0);            stage_ht(j0 + 3);
    if (i + 1 < niter) { VMC2(); } else { VMC0(); }
    BAR(); mm(1, 0); BAR();
    rdA(1, 0); rdB(1, 0); stage_ht(j0 + 4); BAR(); mm(0, 0); BAR();
    rdB(1, 1);            stage_ht(j0 + 5); BAR(); mm(0, 1); BAR();
    rdA(1, 1);            stage_ht(j0 + 6); BAR(); mm(1, 1); BAR();
    rdB(1, 0);            stage_ht(j0 + 7); VMC2(); BAR(); mm(1, 0); BAR();
  }

#pragma unroll
  for (int mi = 0; mi < 8; ++mi) {
#pragma unroll
    for (int ni = 0; ni < 4; ++ni) {
      const int n = tn * 256 + wn * 64 + ni * 16 + c;
#pragma unroll
      for (int e = 0; e < 4; ++e) {
        const int m = tm * 256 + wm * 128 + mi * 16 + g * 4 + e;
        float v = acc[mi][ni][e];
        if (EPI == 4) {
          unsigned short* O = (unsigned short*)outp;
          if (n < 1024) {
            v = (v + b0[n]) * 0.18033688f;
            size_t idx = ((size_t)(m >> 11) * NH + (n >> 6)) * (TQ * HD) +
                         (size_t)(m & (TQ - 1)) * HD + (n & (HD - 1));
            O[idx] = f2bf(v);
          } else {
            int nn = n - 1024;
            v += b1[nn];
            size_t idx = 8388608 + ((size_t)(m >> 11) * NH + (nn >> 6)) * (TQ * HD) +
                         (size_t)(m & (TQ - 1)) * HD + (nn & (HD - 1));
            O[idx] = f2bf(v);
          }
        }
      }
    }
  }
}

// ---------------- 128x256 4-phase GEMM — Vt (col-major) / proj (row-major) ----------
template <int EPI, int ROWMAJ>
__global__ __launch_bounds__(512, 2) void gemm128x256_kernel(
    const unsigned short* __restrict__ A,
    const unsigned short* __restrict__ Bt,
    const float* __restrict__ b0, const float* __restrict__ b1,
    void* __restrict__ outp,
    int M, int N, int K) {
  __shared__ __align__(16) char lds[98304];

  const int tid = (int)threadIdx.x;
  const int w = tid >> 6, lane = tid & 63;
  const int g = lane >> 4, c = lane & 15;
  const int wm = w >> 2, wn = w & 3;

  const int nbm = M >> 7, nbn = N >> 8;
  const int nwg = nbm * nbn;
  int id = (int)blockIdx.x;
  const int cpx = nwg >> 3;
  id = (id & 7) * cpx + (id >> 3);
  const int tm = ROWMAJ ? (id / nbn) : (id % nbm);
  const int tn = ROWMAJ ? (id % nbn) : (id / nbm);

  const char* Ab = (const char*)(A + (size_t)tm * 128 * K);
  const char* Bb = (const char*)(Bt + (size_t)tn * 256 * K);
  const int rowB = K * 2;
  const int nt = K >> 6;

  auto stageA = [&](int t) {
    if (t >= nt) return;
    char* dst = lds + (t & 1) * 49152 + (w << 11);
    const char* s = Ab + (size_t)(w * 16 + c) * rowB + t * 128 + g * 16;
    gload_lds16(s, dst);
    gload_lds16(s + 64, dst + 1024);
  };
  auto stageB = [&](int t, int odd) {
    if (t >= nt) return;
    const int n16 = (w >> 1) * 4 + 2 * odd + (w & 1);
    char* dst = lds + (t & 1) * 49152 + 16384 + (n16 << 11);
    const char* s = Bb + (size_t)(n16 * 16 + c) * rowB + t * 128 + g * 16;
    gload_lds16(s, dst);
    gload_lds16(s + 64, dst + 1024);
  };

  f32x4 acc[4][4];
#pragma unroll
  for (int i = 0; i < 4; ++i)
#pragma unroll
    for (int j = 0; j < 4; ++j) acc[i][j] = (f32x4){0.f, 0.f, 0.f, 0.f};
  bf16x8 af[2][2], bv[2][2][2];

  auto rdA = [&](int cur, int ms) {
#pragma unroll
    for (int mi2 = 0; mi2 < 2; ++mi2)
#pragma unroll
      for (int ki = 0; ki < 2; ++ki)
        af[mi2][ki] = *(const bf16x8*)(lds + cur * 49152 +
            (((wm * 4 + ms * 2 + mi2) << 1) + ki) * 1024 + lane * 16);
  };
  auto rdB = [&](int cur, int ns) {
#pragma unroll
    for (int ni2 = 0; ni2 < 2; ++ni2)
#pragma unroll
      for (int ki = 0; ki < 2; ++ki)
        bv[ns][ni2][ki] = *(const bf16x8*)(lds + cur * 49152 + 16384 +
            (((wn * 4 + ns * 2 + ni2) << 1) + ki) * 1024 + lane * 16);
  };
  auto mm = [&](int ms, int ns) {
    __builtin_amdgcn_s_setprio(1);
#pragma unroll
    for (int mi2 = 0; mi2 < 2; ++mi2)
#pragma unroll
      for (int ni2 = 0; ni2 < 2; ++ni2)
#pragma unroll
        for (int ki = 0; ki < 2; ++ki)
          acc[ms * 2 + mi2][ns * 2 + ni2] = __builtin_amdgcn_mfma_f32_16x16x32_bf16(
              af[mi2][ki], bv[ns][ni2][ki], acc[ms * 2 + mi2][ns * 2 + ni2], 0, 0, 0);
    __builtin_amdgcn_s_setprio(0);
  };

  stageA(0); stageB(0, 0); stageB(0, 1);
  VMC2();
  BAR();

#pragma unroll 1
  for (int i = 0; i < (nt >> 1); ++i) {
    const int t0 = 2 * i, t1 = 2 * i + 1;
    rdA(0, 0); rdB(0, 0); stageA(t0 + 1);
    mm(0, 0); VMC2(); BAR();
    rdB(0, 1); stageB(t0 + 1, 0);
    mm(0, 1); BAR();
    rdA(0, 1); stageB(t0 + 1, 1);
    mm(1, 1); BAR();
    mm(1, 0); VMC2(); BAR();
    rdA(1, 0); rdB(1, 0); stageA(t1 + 1);
    mm(0, 0);
    if (t1 == nt - 1) { VMC0(); } else { VMC2(); }
    BAR();
    rdB(1, 1); stageB(t1 + 1, 0);
    mm(0, 1); BAR();
    rdA(1, 1); stageB(t1 + 1, 1);
    mm(1, 1); BAR();
    mm(1, 0); VMC2(); BAR();
  }

#pragma unroll
  for (int mi = 0; mi < 4; ++mi) {
#pragma unroll
    for (int ni = 0; ni < 4; ++ni) {
      const int n = tn * 256 + wn * 64 + ni * 16 + c;
#pragma unroll
      for (int e = 0; e < 4; ++e) {
        const int m = tm * 128 + wm * 64 + mi * 16 + g * 4 + e;
        float v = acc[mi][ni][e];
        if (EPI == 1) {
          v += b0[m];
          size_t idx = ((size_t)(n >> 11) * (NH * HD) + m) * TQ + (n & (TQ - 1));
          ((unsigned short*)outp)[idx] = f2bf(v);
        } else if (EPI == 2) {
          v += b0[n];
          ((float*)outp)[(size_t)m * N + n] = v;
        }
      }
    }
  }
}

// ---------------- flash attention: DUAL-HEAD blocks (R14) ---------------------------
// Block z: k=z>>8, r=z&255, u=r&7, bhp=r>>3; qt = k?15-u:u; heads bh0=2*bhp, bh1=2*bhp+1.
// Both streams share qt (same trip count / mask); co-resident {z,z+256}: same bhp,
// complementary qt (u,15-u) -> per-CU work constant (34 units) + shared K/V in L2.
// In-wave overlap: QK^T(B) MFMAs retire under softmax(A) VALU; PV(A) under softmax(B).
// LDS 64KB/block (2 blk/CU): per buf {K_A,K_B,V_A,V_B} x 8KB, fragment-order.
__global__ __launch_bounds__(256, 2) void attn_kernel(
    const unsigned short* __restrict__ Q,
    const unsigned short* __restrict__ K,
    const unsigned short* __restrict__ Vt,
    unsigned short* __restrict__ Y) {
  __shared__ __align__(16) char L[2][32768];

  const int tid = (int)threadIdx.x;
  const int w = tid >> 6, lane = tid & 63;
  const int l31 = lane & 31, hi = lane >> 5;

  const int z = (int)blockIdx.x;
  const int kk = z >> 8, r_ = z & 255;
  const int u = r_ & 7, bhp = r_ >> 3;
  const int qt = kk ? (15 - u) : u;
  const int bh0 = 2 * bhp, bh1 = 2 * bhp + 1;
  const int b0i = bh0 >> 4, h0 = bh0 & 15;
  const int b1i = bh1 >> 4, h1 = bh1 & 15;

  const unsigned short* QbA = Q + (size_t)bh0 * TQ * HD;
  const unsigned short* QbB = Q + (size_t)bh1 * TQ * HD;
  const char* KbA = (const char*)(K + (size_t)bh0 * TQ * HD);
  const char* KbB = (const char*)(K + (size_t)bh1 * TQ * HD);
  const char* VbA = (const char*)(Vt + (size_t)bh0 * HD * TQ);
  const char* VbB = (const char*)(Vt + (size_t)bh1 * HD * TQ);

  auto stage = [&](int buf, int kt) {
#pragma unroll
    for (int i = 0; i < 2; ++i) {
      const int s = i * 256 + tid;
      const int r32 = (s >> 8) * 32 + (s & 31);
      const int ck = ((s >> 6) & 3) * 32 + ((s >> 5) & 1) * 16;
      const int doff = i * 4096 + (w << 10);
      char* base = &L[buf][0];
      gload_lds16(KbA + (size_t)kt * 8192 + r32 * 128 + ck, base + doff);
      gload_lds16(KbB + (size_t)kt * 8192 + r32 * 128 + ck, base + 8192 + doff);
      gload_lds16(VbA + (size_t)r32 * 4096 + kt * 128 + ck, base + 16384 + doff);
      gload_lds16(VbB + (size_t)r32 * 4096 + kt * 128 + ck, base + 24576 + doff);
    }
  };

  const int q0 = qt * 128 + w * 32;
  const int qg = q0 + l31;
  const int nkv = 2 * qt + 2;

  stage(0, 0);

  bf16x8 qfA[4], qfB[4];
#pragma unroll
  for (int dk = 0; dk < 4; ++dk) {
    qfA[dk] = *(const bf16x8*)(QbA + (size_t)qg * HD + dk * 16 + hi * 8);
    qfB[dk] = *(const bf16x8*)(QbB + (size_t)qg * HD + dk * 16 + hi * 8);
  }

  f32x16 oacA[2], oacB[2];
#pragma unroll
  for (int nb = 0; nb < 2; ++nb)
#pragma unroll
    for (int r = 0; r < 16; ++r) { oacA[nb][r] = 0.f; oacB[nb][r] = 0.f; }
  float mrA = -3.0e38f, lrA = 0.f, mrB = -3.0e38f, lrB = 0.f;

  __syncthreads();

  for (int kt = 0; kt < nkv; ++kt) {
    const int cur = kt & 1;
    if (kt + 1 < nkv) stage(cur ^ 1, kt + 1);

    if (kt * 64 <= q0 + 31) {
      const char* KlA = &L[cur][0] + lane * 16;
      const char* KlB = KlA + 8192;
      const char* VlA = KlA + 16384;
      const char* VlB = KlA + 24576;

      // QK^T for both heads first: B's MFMAs retire under A's softmax VALU.
      f32x16 sA0, sA1, sB0, sB1;
#pragma unroll
      for (int r = 0; r < 16; ++r) { sA0[r] = 0.f; sA1[r] = 0.f; sB0[r] = 0.f; sB1[r] = 0.f; }
#pragma unroll
      for (int dk = 0; dk < 4; ++dk) {
        bf16x8 kf0 = *(const bf16x8*)(KlA + (dk << 10));
        bf16x8 kf1 = *(const bf16x8*)(KlA + ((4 + dk) << 10));
        sA0 = __builtin_amdgcn_mfma_f32_32x32x16_bf16(kf0, qfA[dk], sA0, 0, 0, 0);
        sA1 = __builtin_amdgcn_mfma_f32_32x32x16_bf16(kf1, qfA[dk], sA1, 0, 0, 0);
      }
#pragma unroll
      for (int dk = 0; dk < 4; ++dk) {
        bf16x8 kf0 = *(const bf16x8*)(KlB + (dk << 10));
        bf16x8 kf1 = *(const bf16x8*)(KlB + ((4 + dk) << 10));
        sB0 = __builtin_amdgcn_mfma_f32_32x32x16_bf16(kf0, qfB[dk], sB0, 0, 0, 0);
        sB1 = __builtin_amdgcn_mfma_f32_32x32x16_bf16(kf1, qfB[dk], sB1, 0, 0, 0);
      }

      const bool maskT = (kt * 64 + 63 > q0);
      if (maskT) {
#pragma unroll
        for (int r = 0; r < 16; ++r) {
          int kv0 = kt * 64 + ((r & 3) + 8 * (r >> 2)) + 4 * hi;
          bool ok0 = (kv0 <= qg), ok1 = (kv0 + 32 <= qg);
          sA0[r] = ok0 ? sA0[r] : -3.0e38f;
          sA1[r] = ok1 ? sA1[r] : -3.0e38f;
          sB0[r] = ok0 ? sB0[r] : -3.0e38f;
          sB1[r] = ok1 ? sB1[r] : -3.0e38f;
        }
      }

      // ---- stream A: softmax + pack + PV (PV's MFMAs overlap B's softmax below) ----
      {
        float mt_ = sA0[0];
#pragma unroll
        for (int r = 1; r < 16; ++r) mt_ = fmaxf(mt_, sA0[r]);
#pragma unroll
        for (int r = 0; r < 16; ++r) mt_ = fmaxf(mt_, sA1[r]);
        mt_ = fmaxf(mt_, __shfl_xor(mt_, 32));
        if (!__all(mt_ - mrA <= 8.0f)) {
          const float mn = fmaxf(mrA, mt_);
          const float al = exp2_fast(mrA - mn);
          mrA = mn;
          lrA *= al;
#pragma unroll
          for (int nb = 0; nb < 2; ++nb)
#pragma unroll
            for (int r = 0; r < 16; ++r) oacA[nb][r] *= al;
        }
        float rs = 0.f;
#pragma unroll
        for (int r = 0; r < 16; ++r) { sA0[r] = exp2_fast(sA0[r] - mrA); rs += sA0[r]; }
#pragma unroll
        for (int r = 0; r < 16; ++r) { sA1[r] = exp2_fast(sA1[r] - mrA); rs += sA1[r]; }
        rs += __shfl_xor(rs, 32);
        lrA += rs;

        bf16x8 pf[4];
        {
          unsigned a0 = cvtpk(sA0[0], sA0[1]), b0 = cvtpk(sA0[2], sA0[3]);
          unsigned c0 = cvtpk(sA0[4], sA0[5]), d0 = cvtpk(sA0[6], sA0[7]);
          plswap(a0, c0); plswap(b0, d0);
          unsigned a1 = cvtpk(sA0[8], sA0[9]), b1 = cvtpk(sA0[10], sA0[11]);
          unsigned c1 = cvtpk(sA0[12], sA0[13]), d1 = cvtpk(sA0[14], sA0[15]);
          plswap(a1, c1); plswap(b1, d1);
          unsigned a2 = cvtpk(sA1[0], sA1[1]), b2 = cvtpk(sA1[2], sA1[3]);
          unsigned c2 = cvtpk(sA1[4], sA1[5]), d2 = cvtpk(sA1[6], sA1[7]);
          plswap(a2, c2); plswap(b2, d2);
          unsigned a3 = cvtpk(sA1[8], sA1[9]), b3 = cvtpk(sA1[10], sA1[11]);
          unsigned c3 = cvtpk(sA1[12], sA1[13]), d3 = cvtpk(sA1[14], sA1[15]);
          plswap(a3, c3); plswap(b3, d3);
          union { unsigned u[4]; bf16x8 v; } t;
          t.u[0] = a0; t.u[1] = b0; t.u[2] = c0; t.u[3] = d0; pf[0] = t.v;
          t.u[0] = a1; t.u[1] = b1; t.u[2] = c1; t.u[3] = d1; pf[1] = t.v;
          t.u[0] = a2; t.u[1] = b2; t.u[2] = c2; t.u[3] = d2; pf[2] = t.v;
          t.u[0] = a3; t.u[1] = b3; t.u[2] = c3; t.u[3] = d3; pf[3] = t.v;
        }
#pragma unroll
        for (int nb = 0; nb < 2; ++nb)
#pragma unroll
          for (int ks = 0; ks < 4; ++ks) {
            bf16x8 vf = *(const bf16x8*)(VlA + (((nb << 2) + ks) << 10));
            oacA[nb] = __builtin_amdgcn_mfma_f32_32x32x16_bf16(vf, pf[ks], oacA[nb], 0, 0, 0);
          }
      }

      // ---- stream B: softmax + pack + PV ----
      {
        float mt_ = sB0[0];
#pragma unroll
        for (int r = 1; r < 16; ++r) mt_ = fmaxf(mt_, sB0[r]);
#pragma unroll
        for (int r = 0; r < 16; ++r) mt_ = fmaxf(mt_, sB1[r]);
        mt_ = fmaxf(mt_, __shfl_xor(mt_, 32));
        if (!__all(mt_ - mrB <= 8.0f)) {
          const float mn = fmaxf(mrB, mt_);
          const float al = exp2_fast(mrB - mn);
          mrB = mn;
          lrB *= al;
#pragma unroll
          for (int nb = 0; nb < 2; ++nb)
#pragma unroll
            for (int r = 0; r < 16; ++r) oacB[nb][r] *= al;
        }
        float rs = 0.f;
#pragma unroll
        for (int r = 0; r < 16; ++r) { sB0[r] = exp2_fast(sB0[r] - mrB); rs += sB0[r]; }
#pragma unroll
        for (int r = 0; r < 16; ++r) { sB1[r] = exp2_fast(sB1[r] - mrB); rs += sB1[r]; }
        rs += __shfl_xor(rs, 32);
        lrB += rs;

        bf16x8 pf[4];
        {
          unsigned a0 = cvtpk(sB0[0], sB0[1]), b0 = cvtpk(sB0[2], sB0[3]);
          unsigned c0 = cvtpk(sB0[4], sB0[5]), d0 = cvtpk(sB0[6], sB0[7]);
          plswap(a0, c0); plswap(b0, d0);
          unsigned a1 = cvtpk(sB0[8], sB0[9]), b1 = cvtpk(sB0[10], sB0[11]);
          unsigned c1 = cvtpk(sB0[12], sB0[13]), d1 = cvtpk(sB0[14], sB0[15]);
          plswap(a1, c1); plswap(b1, d1);
          unsigned a2 = cvtpk(sB1[0], sB1[1]), b2 = cvtpk(sB1[2], sB1[3]);
          unsigned c2 = cvtpk(sB1[4], sB1[5]), d2 = cvtpk(sB1[6], sB1[7]);
          plswap(a2, c2); plswap(b2, d2);
          unsigned a3 = cvtpk(sB1[8], sB1[9]), b3 = cvtpk(sB1[10], sB1[11]);
          unsigned c3 = cvtpk(sB1[12], sB1[13]), d3 = cvtpk(sB1[14], sB1[15]);
          plswap(a3, c3); plswap(b3, d3);
          union { unsigned u[4]; bf16x8 v; } t;
          t.u[0] = a0; t.u[1] = b0; t.u[2] = c0; t.u[3] = d0; pf[0] = t.v;
          t.u[0] = a1; t.u[1] = b1; t.u[2] = c1; t.u[3] = d1; pf[1] = t.v;
          t.u[0] = a2; t.u[1] = b2; t.u[2] = c2; t.u[3] = d2; pf[2] = t.v;
          t.u[0] = a3; t.u[1] = b3; t.u[2] = c3; t.u[3] = d3; pf[3] = t.v;
        }
#pragma unroll
        for (int nb = 0; nb < 2; ++nb)
#pragma unroll
          for (int ks = 0; ks < 4; ++ks) {
            bf16x8 vf = *(const bf16x8*)(VlB + (((nb << 2) + ks) << 10));
            oacB[nb] = __builtin_amdgcn_mfma_f32_32x32x16_bf16(vf, pf[ks], oacB[nb], 0, 0, 0);
          }
      }
    }
    __syncthreads();
  }

  // epilogues
  float invA, invB;
  asm("v_rcp_f32 %0, %1" : "=v"(invA) : "v"(lrA));
  asm("v_rcp_f32 %0, %1" : "=v"(invB) : "v"(lrB));
  unsigned short* YrowA = Y + (size_t)(b0i * TQ + qg) * CDIM + h0 * 64;
  unsigned short* YrowB = Y + (size_t)(b1i * TQ + qg) * CDIM + h1 * 64;
#pragma unroll
  for (int nb = 0; nb < 2; ++nb)
#pragma unroll
    for (int j = 0; j < 8; ++j) {
      const int dbase = ((2 * j) & 3) + 8 * (j >> 1);
      unsigned loA = f2bf(oacA[nb][2 * j] * invA);
      unsigned hiA = f2bf(oacA[nb][2 * j + 1] * invA);
      *(unsigned*)(YrowA + nb * 32 + dbase + 4 * hi) = loA | (hiA << 16);
      unsigned loB = f2bf(oacB[nb][2 * j] * invB);
      unsigned hiB = f2bf(oacB[nb][2 * j + 1] * invB);
      *(unsigned*)(YrowB + nb * 32 + dbase + 4 * hi) = loB | (hiB << 16);
    }
}

// ---------------- launcher ----------------
extern "C" void kernel_launch(void* const* d_in, const int* in_sizes, int n_in,
                              void* d_out, int out_size, void* d_ws, size_t ws_size,
                              hipStream_t stream) {
  (void)in_sizes; (void)n_in; (void)out_size; (void)ws_size;
  const float* x  = (const float*)d_in[0];
  const float* Wq = (const float*)d_in[1];
  const float* bq = (const float*)d_in[2];
  const float* Wk = (const float*)d_in[3];
  const float* bk = (const float*)d_in[4];
  const float* Wv = (const float*)d_in[5];
  const float* bv = (const float*)d_in[6];
  const float* Wp = (const float*)d_in[7];
  const float* bp = (const float*)d_in[8];
  float* out = (float*)d_out;

  char* ws = (char*)d_ws;
  unsigned short* xb  = (unsigned short*)(ws + 0);
  unsigned short* wqb = (unsigned short*)(ws + 16777216);
  unsigned short* wvb = (unsigned short*)(ws + 20971520);
  unsigned short* wpb = (unsigned short*)(ws + 23068672);
  unsigned short* Qh  = (unsigned short*)(ws + 25165824);
  unsigned short* Kh  = (unsigned short*)(ws + 41943040);
  unsigned short* Vt  = (unsigned short*)(ws + 58720256);
  unsigned short* y   = (unsigned short*)(ws + 75497472);

  cvt_all_kernel<<<8192, 256, 0, stream>>>(x, Wq, Wk, Wv, Wp, xb, wqb);

  gemm256_kernel<4><<<256, 512, 0, stream>>>(xb, wqb, bq, bk, Qh, 8192, 2048, 1024);
  gemm128x256_kernel<1, 0><<<256, 512, 0, stream>>>(wvb, xb, bv, bv, Vt, 1024, 8192, 1024);

  attn_kernel<<<512, 256, 0, stream>>>(Qh, Kh, Vt, y);

  gemm128x256_kernel<2, 1><<<256, 512, 0, stream>>>(y, wpb, bp, bp, out, 8192, 1024, 1024);
}

// Round 15
// 196.832 us; speedup vs baseline: 1.0235x; 1.0235x over previous
//
#include <hip/hip_runtime.h>
#include <hip/hip_bf16.h>
#include <cstdint>
#include <cstddef>

#define TQ 2048
#define CDIM 1024
#define NH 16
#define HD 64

typedef __attribute__((ext_vector_type(8))) short bf16x8;
typedef __attribute__((ext_vector_type(4))) float f32x4;
typedef __attribute__((ext_vector_type(16))) float f32x16;

__device__ __forceinline__ unsigned short f2bf(float f) {
  union { float f; unsigned u; } x; x.f = f;
  unsigned r = x.u + 0x7fffu + ((x.u >> 16) & 1u);
  return (unsigned short)(r >> 16);
}

__device__ __forceinline__ unsigned cvtpk(float lo, float hi) {
  unsigned r;
  asm("v_cvt_pk_bf16_f32 %0, %1, %2" : "=v"(r) : "v"(lo), "v"(hi));
  return r;
}

__device__ __forceinline__ void plswap(unsigned& x, unsigned& y) {
  asm("v_permlane32_swap_b32 %0, %1" : "+v"(x), "+v"(y));
}

__device__ __forceinline__ float exp2_fast(float x) {
  float r;
  asm("v_exp_f32 %0, %1" : "=v"(r) : "v"(x));
  return r;
}

__device__ __forceinline__ void gload_lds16(const void* g, void* l) {
  typedef __attribute__((address_space(1))) const void gv;
  typedef __attribute__((address_space(3))) void lv;
  __builtin_amdgcn_global_load_lds((gv*)g, (lv*)l, 16, 0, 0);
}

#define BAR() do { asm volatile("" ::: "memory"); __builtin_amdgcn_s_barrier(); asm volatile("" ::: "memory"); } while (0)
#define VMC2() asm volatile("s_waitcnt vmcnt(2)" ::: "memory")
#define VMC0() asm volatile("s_waitcnt vmcnt(0)" ::: "memory")

// ---------------- fused fp32 -> bf16 converts (x + 4 weights, one dispatch) --------
__global__ void cvt_all_kernel(const float* __restrict__ x,
                               const float* __restrict__ w0, const float* __restrict__ w1,
                               const float* __restrict__ w2, const float* __restrict__ w3,
                               unsigned short* __restrict__ xb,
                               unsigned short* __restrict__ wb) {
  const int bid = (int)blockIdx.x;
  if (bid < 4096) {
    for (int i = bid * 256 + threadIdx.x; i < 2097152; i += 4096 * 256) {
      float4 v = *(const float4*)(x + (size_t)i * 4);
      ushort4 o;
      o.x = f2bf(v.x); o.y = f2bf(v.y); o.z = f2bf(v.z); o.w = f2bf(v.w);
      *(ushort4*)(xb + (size_t)i * 4) = o;
    }
  } else {
    int i = (bid - 4096) * 256 + threadIdx.x;
    int which = i >> 18;
    const float* src = which == 0 ? w0 : which == 1 ? w1 : which == 2 ? w2 : w3;
    int off = (i & 262143) * 4;
    float4 v = *(const float4*)(src + off);
    ushort4 o;
    o.x = f2bf(v.x); o.y = f2bf(v.y); o.z = f2bf(v.z); o.w = f2bf(v.w);
    *(ushort4*)(wb + (size_t)i * 4) = o;
  }
}

// ---------------- 256x256 8-phase GEMM — used for QK (row-major decode) -------------
// EPI 4: fused QK: n<1024 -> Q*0.125*log2e [B,H,T,D] (b0); else K at +8M elems (b1)
template <int EPI>
__global__ __launch_bounds__(512, 2) void gemm256_kernel(
    const unsigned short* __restrict__ A,
    const unsigned short* __restrict__ Bt,
    const float* __restrict__ b0, const float* __restrict__ b1,
    void* __restrict__ outp,
    int M, int N, int K) {
  __shared__ __align__(16) char lds[131072];

  const int tid = (int)threadIdx.x;
  const int w = tid >> 6, lane = tid & 63;
  const int g = lane >> 4, c = lane & 15;
  const int wm = w >> 2, wn = w & 3;

  const int nbm = M >> 8, nbn = N >> 8;
  const int nwg = nbm * nbn;
  int id = (int)blockIdx.x;
  const int cpx = nwg >> 3;
  id = (id & 7) * cpx + (id >> 3);
  const int tn = id % nbn, tm = id / nbn;

  const char* Ab = (const char*)(A + (size_t)tm * 256 * K);
  const char* Bb = (const char*)(Bt + (size_t)tn * 256 * K);
  const int rowB = K * 2;
  const int nht = (K >> 6) << 2;

  char* aw = lds + wm * 16384;
  char* bw = lds + 65536 + (wn >> 1) * 16384;
  const int bfo = (wn & 1) * 8;

  auto stage_ht = [&](int j) {
    if (j >= nht) return;
    const int t = j >> 2, part = j & 3;
    const int isB = part >> 1, half = part & 1;
    const char* src = isB ? Bb : Ab;
    char* dst = lds + isB * 65536 + (t & 1) * 32768 + half * 16384 + w * 2048;
#pragma unroll
    for (int r = 0; r < 2; ++r) {
      const int f = w * 2 + r;
      const int m16 = f >> 1, ki = f & 1;
      gload_lds16(src + (size_t)(half * 128 + m16 * 16 + c) * rowB +
                      t * 128 + ki * 64 + g * 16,
                  dst + r * 1024);
    }
  };

  f32x4 acc[8][4];
#pragma unroll
  for (int i = 0; i < 8; ++i)
#pragma unroll
    for (int j = 0; j < 4; ++j) acc[i][j] = (f32x4){0.f, 0.f, 0.f, 0.f};
  bf16x8 af[4][2], bv[2][2];

  auto rdA = [&](int buf, int ms) {
#pragma unroll
    for (int mi = 0; mi < 4; ++mi)
#pragma unroll
      for (int ki = 0; ki < 2; ++ki)
        af[mi][ki] = *(const bf16x8*)(aw + buf * 32768 +
                                      ((ms * 4 + mi) * 2 + ki) * 1024 + lane * 16);
  };
  auto rdB = [&](int buf, int ns) {
#pragma unroll
    for (int ni = 0; ni < 2; ++ni)
#pragma unroll
      for (int ki = 0; ki < 2; ++ki)
        bv[ni][ki] = *(const bf16x8*)(bw + buf * 32768 +
                                      (bfo + (ns * 2 + ni) * 2 + ki) * 1024 + lane * 16);
  };
  auto mm = [&](int ms, int ns) {
    __builtin_amdgcn_s_setprio(1);
#pragma unroll
    for (int mi = 0; mi < 4; ++mi)
#pragma unroll
      for (int ni = 0; ni < 2; ++ni)
#pragma unroll
        for (int ki = 0; ki < 2; ++ki)
          acc[ms * 4 + mi][ns * 2 + ni] = __builtin_amdgcn_mfma_f32_16x16x32_bf16(
              af[mi][ki], bv[ni][ki], acc[ms * 4 + mi][ns * 2 + ni], 0, 0, 0);
    __builtin_amdgcn_s_setprio(0);
  };

  for (int j = 0; j < 5; ++j) stage_ht(j);
  VMC2();
  BAR();

  const int niter = K >> 7;
#pragma unroll 1
  for (int i = 0; i < niter; ++i) {
    const int j0 = 5 + (i << 3);
    rdA(0, 0); rdB(0, 0); stage_ht(j0 + 0); BAR(); mm(0, 0); BAR();
    rdB(0, 1);            stage_ht(j0 + 1); BAR(); mm(0, 1); BAR();
    rdA(0, 1);            stage_ht(j0 + 2); BAR(); mm(1, 1); BAR();
    rdB(0, 0);            stage_ht(j0 + 3);
    if (i + 1 < niter) { VMC2(); } else { VMC0(); }
    BAR(); mm(1, 0); BAR();
    rdA(1, 0); rdB(1, 0); stage_ht(j0 + 4); BAR(); mm(0, 0); BAR();
    rdB(1, 1);            stage_ht(j0 + 5); BAR(); mm(0, 1); BAR();
    rdA(1, 1);            stage_ht(j0 + 6); BAR(); mm(1, 1); BAR();
    rdB(1, 0);            stage_ht(j0 + 7); VMC2(); BAR(); mm(1, 0); BAR();
  }

#pragma unroll
  for (int mi = 0; mi < 8; ++mi) {
#pragma unroll
    for (int ni = 0; ni < 4; ++ni) {
      const int n = tn * 256 + wn * 64 + ni * 16 + c;
#pragma unroll
      for (int e = 0; e < 4; ++e) {
        const int m = tm * 256 + wm * 128 + mi * 16 + g * 4 + e;
        float v = acc[mi][ni][e];
        if (EPI == 4) {
          unsigned short* O = (unsigned short*)outp;
          if (n < 1024) {
            v = (v + b0[n]) * 0.18033688f;
            size_t idx = ((size_t)(m >> 11) * NH + (n >> 6)) * (TQ * HD) +
                         (size_t)(m & (TQ - 1)) * HD + (n & (HD - 1));
            O[idx] = f2bf(v);
          } else {
            int nn = n - 1024;
            v += b1[nn];
            size_t idx = 8388608 + ((size_t)(m >> 11) * NH + (nn >> 6)) * (TQ * HD) +
                         (size_t)(m & (TQ - 1)) * HD + (nn & (HD - 1));
            O[idx] = f2bf(v);
          }
        }
      }
    }
  }
}

// ---------------- 128x256 4-phase GEMM — Vt (col-major) / proj (row-major) ----------
// EPI 1: bf16 -> [B,H,D,T] (m=h*D+d, n=b*T+t), bias b0[m]
// EPI 2: f32  -> [M,N] row-major, bias b0[n]
template <int EPI, int ROWMAJ>
__global__ __launch_bounds__(512, 2) void gemm128x256_kernel(
    const unsigned short* __restrict__ A,
    const unsigned short* __restrict__ Bt,
    const float* __restrict__ b0, const float* __restrict__ b1,
    void* __restrict__ outp,
    int M, int N, int K) {
  __shared__ __align__(16) char lds[98304];

  const int tid = (int)threadIdx.x;
  const int w = tid >> 6, lane = tid & 63;
  const int g = lane >> 4, c = lane & 15;
  const int wm = w >> 2, wn = w & 3;

  const int nbm = M >> 7, nbn = N >> 8;
  const int nwg = nbm * nbn;
  int id = (int)blockIdx.x;
  const int cpx = nwg >> 3;
  id = (id & 7) * cpx + (id >> 3);
  const int tm = ROWMAJ ? (id / nbn) : (id % nbm);
  const int tn = ROWMAJ ? (id % nbn) : (id / nbm);

  const char* Ab = (const char*)(A + (size_t)tm * 128 * K);
  const char* Bb = (const char*)(Bt + (size_t)tn * 256 * K);
  const int rowB = K * 2;
  const int nt = K >> 6;

  auto stageA = [&](int t) {
    if (t >= nt) return;
    char* dst = lds + (t & 1) * 49152 + (w << 11);
    const char* s = Ab + (size_t)(w * 16 + c) * rowB + t * 128 + g * 16;
    gload_lds16(s, dst);
    gload_lds16(s + 64, dst + 1024);
  };
  auto stageB = [&](int t, int odd) {
    if (t >= nt) return;
    const int n16 = (w >> 1) * 4 + 2 * odd + (w & 1);
    char* dst = lds + (t & 1) * 49152 + 16384 + (n16 << 11);
    const char* s = Bb + (size_t)(n16 * 16 + c) * rowB + t * 128 + g * 16;
    gload_lds16(s, dst);
    gload_lds16(s + 64, dst + 1024);
  };

  f32x4 acc[4][4];
#pragma unroll
  for (int i = 0; i < 4; ++i)
#pragma unroll
    for (int j = 0; j < 4; ++j) acc[i][j] = (f32x4){0.f, 0.f, 0.f, 0.f};
  bf16x8 af[2][2], bv[2][2][2];

  auto rdA = [&](int cur, int ms) {
#pragma unroll
    for (int mi2 = 0; mi2 < 2; ++mi2)
#pragma unroll
      for (int ki = 0; ki < 2; ++ki)
        af[mi2][ki] = *(const bf16x8*)(lds + cur * 49152 +
            (((wm * 4 + ms * 2 + mi2) << 1) + ki) * 1024 + lane * 16);
  };
  auto rdB = [&](int cur, int ns) {
#pragma unroll
    for (int ni2 = 0; ni2 < 2; ++ni2)
#pragma unroll
      for (int ki = 0; ki < 2; ++ki)
        bv[ns][ni2][ki] = *(const bf16x8*)(lds + cur * 49152 + 16384 +
            (((wn * 4 + ns * 2 + ni2) << 1) + ki) * 1024 + lane * 16);
  };
  auto mm = [&](int ms, int ns) {
    __builtin_amdgcn_s_setprio(1);
#pragma unroll
    for (int mi2 = 0; mi2 < 2; ++mi2)
#pragma unroll
      for (int ni2 = 0; ni2 < 2; ++ni2)
#pragma unroll
        for (int ki = 0; ki < 2; ++ki)
          acc[ms * 2 + mi2][ns * 2 + ni2] = __builtin_amdgcn_mfma_f32_16x16x32_bf16(
              af[mi2][ki], bv[ns][ni2][ki], acc[ms * 2 + mi2][ns * 2 + ni2], 0, 0, 0);
    __builtin_amdgcn_s_setprio(0);
  };

  stageA(0); stageB(0, 0); stageB(0, 1);
  VMC2();
  BAR();

#pragma unroll 1
  for (int i = 0; i < (nt >> 1); ++i) {
    const int t0 = 2 * i, t1 = 2 * i + 1;
    rdA(0, 0); rdB(0, 0); stageA(t0 + 1);
    mm(0, 0); VMC2(); BAR();
    rdB(0, 1); stageB(t0 + 1, 0);
    mm(0, 1); BAR();
    rdA(0, 1); stageB(t0 + 1, 1);
    mm(1, 1); BAR();
    mm(1, 0); VMC2(); BAR();
    rdA(1, 0); rdB(1, 0); stageA(t1 + 1);
    mm(0, 0);
    if (t1 == nt - 1) { VMC0(); } else { VMC2(); }
    BAR();
    rdB(1, 1); stageB(t1 + 1, 0);
    mm(0, 1); BAR();
    rdA(1, 1); stageB(t1 + 1, 1);
    mm(1, 1); BAR();
    mm(1, 0); VMC2(); BAR();
  }

#pragma unroll
  for (int mi = 0; mi < 4; ++mi) {
#pragma unroll
    for (int ni = 0; ni < 4; ++ni) {
      const int n = tn * 256 + wn * 64 + ni * 16 + c;
#pragma unroll
      for (int e = 0; e < 4; ++e) {
        const int m = tm * 128 + wm * 64 + mi * 16 + g * 4 + e;
        float v = acc[mi][ni][e];
        if (EPI == 1) {
          v += b0[m];
          size_t idx = ((size_t)(n >> 11) * (NH * HD) + m) * TQ + (n & (TQ - 1));
          ((unsigned short*)outp)[idx] = f2bf(v);
        } else if (EPI == 2) {
          v += b0[n];
          ((float*)outp)[(size_t)m * N + n] = v;
        }
      }
    }
  }
}

// ---------------- flash attention (exact R13/R11 body — measured best 68.3 us) ------
// R14 lesson: dual-head (64KB LDS, 2 blk/CU) traded 16->8 waves/CU for in-wave ILP
// and lost 10%; wave-level MFMA/VALU overlap at 4 blk/CU was already doing that job.
__global__ __launch_bounds__(256, 4) void attn_kernel(
    const unsigned short* __restrict__ Q,
    const unsigned short* __restrict__ K,
    const unsigned short* __restrict__ Vt,
    unsigned short* __restrict__ Y) {
  __shared__ __align__(16) char Ks[2][8192];
  __shared__ __align__(16) char Vs[2][8192];

  const int tid = (int)threadIdx.x;
  const int w = tid >> 6, lane = tid & 63;
  const int l31 = lane & 31, hi = lane >> 5;

  const int n = (int)blockIdx.x;
  const int g = n & 255, k = n >> 8;
  const int bh = g >> 2;
  const int u = 2 * (g & 3) + (k >> 1);
  const int qt = (k & 1) ? (15 - u) : u;
  const int b = bh >> 4, h = bh & 15;

  const unsigned short* Qb = Q + (size_t)bh * TQ * HD;
  const char* Kb = (const char*)(K + (size_t)bh * TQ * HD);
  const char* Vb = (const char*)(Vt + (size_t)bh * HD * TQ);

  auto stage = [&](int buf, int kt) {
#pragma unroll
    for (int i = 0; i < 2; ++i) {
      const int s = i * 256 + tid;
      const int r32 = (s >> 8) * 32 + (s & 31);
      const int ck = ((s >> 6) & 3) * 32 + ((s >> 5) & 1) * 16;
      char* kdst = &Ks[buf][0] + i * 4096 + (w << 10);
      char* vdst = &Vs[buf][0] + i * 4096 + (w << 10);
      gload_lds16(Kb + (size_t)kt * 8192 + r32 * 128 + ck, kdst);
      gload_lds16(Vb + (size_t)r32 * 4096 + kt * 128 + ck, vdst);
    }
  };

  const int q0 = qt * 128 + w * 32;
  const int qg = q0 + l31;
  const int nkv = 2 * qt + 2;

  stage(0, 0);

  bf16x8 qf[4];
#pragma unroll
  for (int dk = 0; dk < 4; ++dk)
    qf[dk] = *(const bf16x8*)(Qb + (size_t)qg * HD + dk * 16 + hi * 8);

  f32x16 oac[2];
#pragma unroll
  for (int nb = 0; nb < 2; ++nb)
#pragma unroll
    for (int r = 0; r < 16; ++r) oac[nb][r] = 0.f;
  float mr = -3.0e38f, lr = 0.f;

  __syncthreads();

  for (int kt = 0; kt < nkv; ++kt) {
    const int cur = kt & 1;
    if (kt + 1 < nkv) stage(cur ^ 1, kt + 1);

    if (kt * 64 <= q0 + 31) {
      const char* Klane = &Ks[cur][0] + lane * 16;
      const char* Vlane = &Vs[cur][0] + lane * 16;

      f32x16 s0, s1;
#pragma unroll
      for (int r = 0; r < 16; ++r) { s0[r] = 0.f; s1[r] = 0.f; }
#pragma unroll
      for (int dk = 0; dk < 4; ++dk) {
        bf16x8 kf0 = *(const bf16x8*)(Klane + (dk << 10));
        bf16x8 kf1 = *(const bf16x8*)(Klane + ((4 + dk) << 10));
        s0 = __builtin_amdgcn_mfma_f32_32x32x16_bf16(kf0, qf[dk], s0, 0, 0, 0);
        s1 = __builtin_amdgcn_mfma_f32_32x32x16_bf16(kf1, qf[dk], s1, 0, 0, 0);
      }

      const bool maskT = (kt * 64 + 63 > q0);
      if (maskT) {
#pragma unroll
        for (int r = 0; r < 16; ++r) {
          int kv0 = kt * 64 + ((r & 3) + 8 * (r >> 2)) + 4 * hi;
          s0[r] = (kv0 <= qg) ? s0[r] : -3.0e38f;
          s1[r] = (kv0 + 32 <= qg) ? s1[r] : -3.0e38f;
        }
      }

      float mt_ = s0[0];
#pragma unroll
      for (int r = 1; r < 16; ++r) mt_ = fmaxf(mt_, s0[r]);
#pragma unroll
      for (int r = 0; r < 16; ++r) mt_ = fmaxf(mt_, s1[r]);
      mt_ = fmaxf(mt_, __shfl_xor(mt_, 32));

      if (!__all(mt_ - mr <= 8.0f)) {
        const float mn = fmaxf(mr, mt_);
        const float al = exp2_fast(mr - mn);
        mr = mn;
        lr *= al;
#pragma unroll
        for (int nb = 0; nb < 2; ++nb)
#pragma unroll
          for (int r = 0; r < 16; ++r) oac[nb][r] *= al;
      }

      float rs = 0.f;
#pragma unroll
      for (int r = 0; r < 16; ++r) { s0[r] = exp2_fast(s0[r] - mr); rs += s0[r]; }
#pragma unroll
      for (int r = 0; r < 16; ++r) { s1[r] = exp2_fast(s1[r] - mr); rs += s1[r]; }
      rs += __shfl_xor(rs, 32);
      lr += rs;

      bf16x8 pf[4];
      {
        unsigned a0 = cvtpk(s0[0], s0[1]), b0 = cvtpk(s0[2], s0[3]);
        unsigned c0 = cvtpk(s0[4], s0[5]), d0 = cvtpk(s0[6], s0[7]);
        plswap(a0, c0); plswap(b0, d0);
        unsigned a1 = cvtpk(s0[8], s0[9]), b1 = cvtpk(s0[10], s0[11]);
        unsigned c1 = cvtpk(s0[12], s0[13]), d1 = cvtpk(s0[14], s0[15]);
        plswap(a1, c1); plswap(b1, d1);
        unsigned a2 = cvtpk(s1[0], s1[1]), b2 = cvtpk(s1[2], s1[3]);
        unsigned c2 = cvtpk(s1[4], s1[5]), d2 = cvtpk(s1[6], s1[7]);
        plswap(a2, c2); plswap(b2, d2);
        unsigned a3 = cvtpk(s1[8], s1[9]), b3 = cvtpk(s1[10], s1[11]);
        unsigned c3 = cvtpk(s1[12], s1[13]), d3 = cvtpk(s1[14], s1[15]);
        plswap(a3, c3); plswap(b3, d3);
        union { unsigned u[4]; bf16x8 v; } t;
        t.u[0] = a0; t.u[1] = b0; t.u[2] = c0; t.u[3] = d0; pf[0] = t.v;
        t.u[0] = a1; t.u[1] = b1; t.u[2] = c1; t.u[3] = d1; pf[1] = t.v;
        t.u[0] = a2; t.u[1] = b2; t.u[2] = c2; t.u[3] = d2; pf[2] = t.v;
        t.u[0] = a3; t.u[1] = b3; t.u[2] = c3; t.u[3] = d3; pf[3] = t.v;
      }

#pragma unroll
      for (int nb = 0; nb < 2; ++nb)
#pragma unroll
        for (int ks = 0; ks < 4; ++ks) {
          bf16x8 vf = *(const bf16x8*)(Vlane + (((nb << 2) + ks) << 10));
          oac[nb] = __builtin_amdgcn_mfma_f32_32x32x16_bf16(vf, pf[ks], oac[nb], 0, 0, 0);
        }
    }
    __syncthreads();
  }

  float inv;
  asm("v_rcp_f32 %0, %1" : "=v"(inv) : "v"(lr));
  unsigned short* Yrow = Y + (size_t)(b * TQ + qg) * CDIM + h * 64;
#pragma unroll
  for (int nb = 0; nb < 2; ++nb)
#pragma unroll
    for (int j = 0; j < 8; ++j) {
      const int dbase = ((2 * j) & 3) + 8 * (j >> 1);
      unsigned lo = f2bf(oac[nb][2 * j] * inv);
      unsigned hi2 = f2bf(oac[nb][2 * j + 1] * inv);
      *(unsigned*)(Yrow + nb * 32 + dbase + 4 * hi) = lo | (hi2 << 16);
    }
}

// ---------------- launcher ----------------
extern "C" void kernel_launch(void* const* d_in, const int* in_sizes, int n_in,
                              void* d_out, int out_size, void* d_ws, size_t ws_size,
                              hipStream_t stream) {
  (void)in_sizes; (void)n_in; (void)out_size; (void)ws_size;
  const float* x  = (const float*)d_in[0];
  const float* Wq = (const float*)d_in[1];
  const float* bq = (const float*)d_in[2];
  const float* Wk = (const float*)d_in[3];
  const float* bk = (const float*)d_in[4];
  const float* Wv = (const float*)d_in[5];
  const float* bv = (const float*)d_in[6];
  const float* Wp = (const float*)d_in[7];
  const float* bp = (const float*)d_in[8];
  float* out = (float*)d_out;

  char* ws = (char*)d_ws;
  unsigned short* xb  = (unsigned short*)(ws + 0);
  unsigned short* wqb = (unsigned short*)(ws + 16777216);
  unsigned short* wvb = (unsigned short*)(ws + 20971520);
  unsigned short* wpb = (unsigned short*)(ws + 23068672);
  unsigned short* Qh  = (unsigned short*)(ws + 25165824);
  unsigned short* Kh  = (unsigned short*)(ws + 41943040);
  unsigned short* Vt  = (unsigned short*)(ws + 58720256);
  unsigned short* y   = (unsigned short*)(ws + 75497472);
  (void)Kh;

  cvt_all_kernel<<<8192, 256, 0, stream>>>(x, Wq, Wk, Wv, Wp, xb, wqb);

  gemm256_kernel<4><<<256, 512, 0, stream>>>(xb, wqb, bq, bk, Qh, 8192, 2048, 1024);
  gemm128x256_kernel<1, 0><<<256, 512, 0, stream>>>(wvb, xb, bv, bv, Vt, 1024, 8192, 1024);

  attn_kernel<<<1024, 256, 0, stream>>>(Qh, Kh, Vt, y);

  gemm128x256_kernel<2, 1><<<256, 512, 0, stream>>>(y, wpb, bp, bp, out, 8192, 1024, 1024);
}

// Round 16
// 190.107 us; speedup vs baseline: 1.0598x; 1.0354x over previous
//
#include <hip/hip_runtime.h>
#include <hip/hip_bf16.h>
#include <cstdint>
#include <cstddef>

#define TQ 2048
#define CDIM 1024
#define NH 16
#define HD 64

typedef __attribute__((ext_vector_type(8))) short bf16x8;
typedef __attribute__((ext_vector_type(4))) float f32x4;
typedef __attribute__((ext_vector_type(16))) float f32x16;

__device__ __forceinline__ unsigned short f2bf(float f) {
  union { float f; unsigned u; } x; x.f = f;
  unsigned r = x.u + 0x7fffu + ((x.u >> 16) & 1u);
  return (unsigned short)(r >> 16);
}

__device__ __forceinline__ unsigned cvtpk(float lo, float hi) {
  unsigned r;
  asm("v_cvt_pk_bf16_f32 %0, %1, %2" : "=v"(r) : "v"(lo), "v"(hi));
  return r;
}

__device__ __forceinline__ void plswap(unsigned& x, unsigned& y) {
  asm("v_permlane32_swap_b32 %0, %1" : "+v"(x), "+v"(y));
}

__device__ __forceinline__ float exp2_fast(float x) {
  float r;
  asm("v_exp_f32 %0, %1" : "=v"(r) : "v"(x));
  return r;
}

__device__ __forceinline__ void gload_lds16(const void* g, void* l) {
  typedef __attribute__((address_space(1))) const void gv;
  typedef __attribute__((address_space(3))) void lv;
  __builtin_amdgcn_global_load_lds((gv*)g, (lv*)l, 16, 0, 0);
}

#define BAR() do { asm volatile("" ::: "memory"); __builtin_amdgcn_s_barrier(); asm volatile("" ::: "memory"); } while (0)
#define VMC2() asm volatile("s_waitcnt vmcnt(2)" ::: "memory")
#define VMC0() asm volatile("s_waitcnt vmcnt(0)" ::: "memory")

// ---------------- fused fp32 -> bf16 converts ----------------
__global__ void cvt_all_kernel(const float* __restrict__ x,
                               const float* __restrict__ w0, const float* __restrict__ w1,
                               const float* __restrict__ w2, const float* __restrict__ w3,
                               unsigned short* __restrict__ xb,
                               unsigned short* __restrict__ wb) {
  const int bid = (int)blockIdx.x;
  if (bid < 4096) {
    for (int i = bid * 256 + threadIdx.x; i < 2097152; i += 4096 * 256) {
      float4 v = *(const float4*)(x + (size_t)i * 4);
      ushort4 o;
      o.x = f2bf(v.x); o.y = f2bf(v.y); o.z = f2bf(v.z); o.w = f2bf(v.w);
      *(ushort4*)(xb + (size_t)i * 4) = o;
    }
  } else {
    int i = (bid - 4096) * 256 + threadIdx.x;
    int which = i >> 18;
    const float* src = which == 0 ? w0 : which == 1 ? w1 : which == 2 ? w2 : w3;
    int off = (i & 262143) * 4;
    float4 v = *(const float4*)(src + off);
    ushort4 o;
    o.x = f2bf(v.x); o.y = f2bf(v.y); o.z = f2bf(v.z); o.w = f2bf(v.w);
    *(ushort4*)(wb + (size_t)i * 4) = o;
  }
}

// ---------------- 256x256 8-phase GEMM body (QK, EPI4) — R13 verbatim ---------------
__device__ __forceinline__ void gemm256_body(
    char* lds, int bid,
    const unsigned short* __restrict__ A,
    const unsigned short* __restrict__ Bt,
    const float* __restrict__ b0, const float* __restrict__ b1,
    void* __restrict__ outp, int M, int N, int K) {
  const int tid = (int)threadIdx.x;
  const int w = tid >> 6, lane = tid & 63;
  const int g = lane >> 4, c = lane & 15;
  const int wm = w >> 2, wn = w & 3;

  const int nbm = M >> 8, nbn = N >> 8;
  const int nwg = nbm * nbn;
  int id = bid;
  const int cpx = nwg >> 3;
  id = (id & 7) * cpx + (id >> 3);
  const int tn = id % nbn, tm = id / nbn;

  const char* Ab = (const char*)(A + (size_t)tm * 256 * K);
  const char* Bb = (const char*)(Bt + (size_t)tn * 256 * K);
  const int rowB = K * 2;
  const int nht = (K >> 6) << 2;

  char* aw = lds + wm * 16384;
  char* bw = lds + 65536 + (wn >> 1) * 16384;
  const int bfo = (wn & 1) * 8;

  auto stage_ht = [&](int j) {
    if (j >= nht) return;
    const int t = j >> 2, part = j & 3;
    const int isB = part >> 1, half = part & 1;
    const char* src = isB ? Bb : Ab;
    char* dst = lds + isB * 65536 + (t & 1) * 32768 + half * 16384 + w * 2048;
#pragma unroll
    for (int r = 0; r < 2; ++r) {
      const int f = w * 2 + r;
      const int m16 = f >> 1, ki = f & 1;
      gload_lds16(src + (size_t)(half * 128 + m16 * 16 + c) * rowB +
                      t * 128 + ki * 64 + g * 16,
                  dst + r * 1024);
    }
  };

  f32x4 acc[8][4];
#pragma unroll
  for (int i = 0; i < 8; ++i)
#pragma unroll
    for (int j = 0; j < 4; ++j) acc[i][j] = (f32x4){0.f, 0.f, 0.f, 0.f};
  bf16x8 af[4][2], bv[2][2];

  auto rdA = [&](int buf, int ms) {
#pragma unroll
    for (int mi = 0; mi < 4; ++mi)
#pragma unroll
      for (int ki = 0; ki < 2; ++ki)
        af[mi][ki] = *(const bf16x8*)(aw + buf * 32768 +
                                      ((ms * 4 + mi) * 2 + ki) * 1024 + lane * 16);
  };
  auto rdB = [&](int buf, int ns) {
#pragma unroll
    for (int ni = 0; ni < 2; ++ni)
#pragma unroll
      for (int ki = 0; ki < 2; ++ki)
        bv[ni][ki] = *(const bf16x8*)(bw + buf * 32768 +
                                      (bfo + (ns * 2 + ni) * 2 + ki) * 1024 + lane * 16);
  };
  auto mm = [&](int ms, int ns) {
    __builtin_amdgcn_s_setprio(1);
#pragma unroll
    for (int mi = 0; mi < 4; ++mi)
#pragma unroll
      for (int ni = 0; ni < 2; ++ni)
#pragma unroll
        for (int ki = 0; ki < 2; ++ki)
          acc[ms * 4 + mi][ns * 2 + ni] = __builtin_amdgcn_mfma_f32_16x16x32_bf16(
              af[mi][ki], bv[ni][ki], acc[ms * 4 + mi][ns * 2 + ni], 0, 0, 0);
    __builtin_amdgcn_s_setprio(0);
  };

  for (int j = 0; j < 5; ++j) stage_ht(j);
  VMC2();
  BAR();

  const int niter = K >> 7;
#pragma unroll 1
  for (int i = 0; i < niter; ++i) {
    const int j0 = 5 + (i << 3);
    rdA(0, 0); rdB(0, 0); stage_ht(j0 + 0); BAR(); mm(0, 0); BAR();
    rdB(0, 1);            stage_ht(j0 + 1); BAR(); mm(0, 1); BAR();
    rdA(0, 1);            stage_ht(j0 + 2); BAR(); mm(1, 1); BAR();
    rdB(0, 0);            stage_ht(j0 + 3);
    if (i + 1 < niter) { VMC2(); } else { VMC0(); }
    BAR(); mm(1, 0); BAR();
    rdA(1, 0); rdB(1, 0); stage_ht(j0 + 4); BAR(); mm(0, 0); BAR();
    rdB(1, 1);            stage_ht(j0 + 5); BAR(); mm(0, 1); BAR();
    rdA(1, 1);            stage_ht(j0 + 6); BAR(); mm(1, 1); BAR();
    rdB(1, 0);            stage_ht(j0 + 7); VMC2(); BAR(); mm(1, 0); BAR();
  }

#pragma unroll
  for (int mi = 0; mi < 8; ++mi) {
#pragma unroll
    for (int ni = 0; ni < 4; ++ni) {
      const int n = tn * 256 + wn * 64 + ni * 16 + c;
#pragma unroll
      for (int e = 0; e < 4; ++e) {
        const int m = tm * 256 + wm * 128 + mi * 16 + g * 4 + e;
        float v = acc[mi][ni][e];
        unsigned short* O = (unsigned short*)outp;
        if (n < 1024) {
          v = (v + b0[n]) * 0.18033688f;
          size_t idx = ((size_t)(m >> 11) * NH + (n >> 6)) * (TQ * HD) +
                       (size_t)(m & (TQ - 1)) * HD + (n & (HD - 1));
          O[idx] = f2bf(v);
        } else {
          int nn = n - 1024;
          v += b1[nn];
          size_t idx = 8388608 + ((size_t)(m >> 11) * NH + (nn >> 6)) * (TQ * HD) +
                       (size_t)(m & (TQ - 1)) * HD + (nn & (HD - 1));
          O[idx] = f2bf(v);
        }
      }
    }
  }
}

// ---------------- 128x256 4-phase GEMM body — R13 verbatim --------------------------
// EPI 1: bf16 -> [B,H,D,T], bias b0[m]  | EPI 2: f32 row-major, bias b0[n]
template <int EPI, int ROWMAJ>
__device__ __forceinline__ void gemm128x256_body(
    char* lds, int bid,
    const unsigned short* __restrict__ A,
    const unsigned short* __restrict__ Bt,
    const float* __restrict__ b0,
    void* __restrict__ outp, int M, int N, int K) {
  const int tid = (int)threadIdx.x;
  const int w = tid >> 6, lane = tid & 63;
  const int g = lane >> 4, c = lane & 15;
  const int wm = w >> 2, wn = w & 3;

  const int nbm = M >> 7, nbn = N >> 8;
  const int nwg = nbm * nbn;
  int id = bid;
  const int cpx = nwg >> 3;
  id = (id & 7) * cpx + (id >> 3);
  const int tm = ROWMAJ ? (id / nbn) : (id % nbm);
  const int tn = ROWMAJ ? (id % nbn) : (id / nbm);

  const char* Ab = (const char*)(A + (size_t)tm * 128 * K);
  const char* Bb = (const char*)(Bt + (size_t)tn * 256 * K);
  const int rowB = K * 2;
  const int nt = K >> 6;

  auto stageA = [&](int t) {
    if (t >= nt) return;
    char* dst = lds + (t & 1) * 49152 + (w << 11);
    const char* s = Ab + (size_t)(w * 16 + c) * rowB + t * 128 + g * 16;
    gload_lds16(s, dst);
    gload_lds16(s + 64, dst + 1024);
  };
  auto stageB = [&](int t, int odd) {
    if (t >= nt) return;
    const int n16 = (w >> 1) * 4 + 2 * odd + (w & 1);
    char* dst = lds + (t & 1) * 49152 + 16384 + (n16 << 11);
    const char* s = Bb + (size_t)(n16 * 16 + c) * rowB + t * 128 + g * 16;
    gload_lds16(s, dst);
    gload_lds16(s + 64, dst + 1024);
  };

  f32x4 acc[4][4];
#pragma unroll
  for (int i = 0; i < 4; ++i)
#pragma unroll
    for (int j = 0; j < 4; ++j) acc[i][j] = (f32x4){0.f, 0.f, 0.f, 0.f};
  bf16x8 af[2][2], bv[2][2][2];

  auto rdA = [&](int cur, int ms) {
#pragma unroll
    for (int mi2 = 0; mi2 < 2; ++mi2)
#pragma unroll
      for (int ki = 0; ki < 2; ++ki)
        af[mi2][ki] = *(const bf16x8*)(lds + cur * 49152 +
            (((wm * 4 + ms * 2 + mi2) << 1) + ki) * 1024 + lane * 16);
  };
  auto rdB = [&](int cur, int ns) {
#pragma unroll
    for (int ni2 = 0; ni2 < 2; ++ni2)
#pragma unroll
      for (int ki = 0; ki < 2; ++ki)
        bv[ns][ni2][ki] = *(const bf16x8*)(lds + cur * 49152 + 16384 +
            (((wn * 4 + ns * 2 + ni2) << 1) + ki) * 1024 + lane * 16);
  };
  auto mm = [&](int ms, int ns) {
    __builtin_amdgcn_s_setprio(1);
#pragma unroll
    for (int mi2 = 0; mi2 < 2; ++mi2)
#pragma unroll
      for (int ni2 = 0; ni2 < 2; ++ni2)
#pragma unroll
        for (int ki = 0; ki < 2; ++ki)
          acc[ms * 2 + mi2][ns * 2 + ni2] = __builtin_amdgcn_mfma_f32_16x16x32_bf16(
              af[mi2][ki], bv[ns][ni2][ki], acc[ms * 2 + mi2][ns * 2 + ni2], 0, 0, 0);
    __builtin_amdgcn_s_setprio(0);
  };

  stageA(0); stageB(0, 0); stageB(0, 1);
  VMC2();
  BAR();

#pragma unroll 1
  for (int i = 0; i < (nt >> 1); ++i) {
    const int t0 = 2 * i, t1 = 2 * i + 1;
    rdA(0, 0); rdB(0, 0); stageA(t0 + 1);
    mm(0, 0); VMC2(); BAR();
    rdB(0, 1); stageB(t0 + 1, 0);
    mm(0, 1); BAR();
    rdA(0, 1); stageB(t0 + 1, 1);
    mm(1, 1); BAR();
    mm(1, 0); VMC2(); BAR();
    rdA(1, 0); rdB(1, 0); stageA(t1 + 1);
    mm(0, 0);
    if (t1 == nt - 1) { VMC0(); } else { VMC2(); }
    BAR();
    rdB(1, 1); stageB(t1 + 1, 0);
    mm(0, 1); BAR();
    rdA(1, 1); stageB(t1 + 1, 1);
    mm(1, 1); BAR();
    mm(1, 0); VMC2(); BAR();
  }

#pragma unroll
  for (int mi = 0; mi < 4; ++mi) {
#pragma unroll
    for (int ni = 0; ni < 4; ++ni) {
      const int n = tn * 256 + wn * 64 + ni * 16 + c;
#pragma unroll
      for (int e = 0; e < 4; ++e) {
        const int m = tm * 128 + wm * 64 + mi * 16 + g * 4 + e;
        float v = acc[mi][ni][e];
        if (EPI == 1) {
          v += b0[m];
          size_t idx = ((size_t)(n >> 11) * (NH * HD) + m) * TQ + (n & (TQ - 1));
          ((unsigned short*)outp)[idx] = f2bf(v);
        } else {
          v += b0[n];
          ((float*)outp)[(size_t)m * N + n] = v;
        }
      }
    }
  }
}

// ---------------- merged QK + Vt dispatch (R16) -------------------------------------
// Blocks 0..255: QK 256^2 8-phase (1 blk/CU, fills chip). Blocks 256..511: Vt
// 128x256 4-phase — backfill CUs as QK blocks retire (tail overlap + one less gap).
__global__ __launch_bounds__(512, 2) void qkvt_kernel(
    const unsigned short* __restrict__ xb,
    const unsigned short* __restrict__ wqb,
    const float* __restrict__ bq, const float* __restrict__ bk,
    unsigned short* __restrict__ Qh,
    const unsigned short* __restrict__ wvb,
    const float* __restrict__ bv,
    unsigned short* __restrict__ Vt) {
  __shared__ __align__(16) char lds[131072];
  const int bid = (int)blockIdx.x;
  if (bid < 256) {
    gemm256_body(lds, bid, xb, wqb, bq, bk, Qh, 8192, 2048, 1024);
  } else {
    gemm128x256_body<1, 0>(lds, bid - 256, wvb, xb, bv, Vt, 1024, 8192, 1024);
  }
}

// ---------------- proj GEMM (standalone, row-major decode) --------------------------
__global__ __launch_bounds__(512, 2) void proj_kernel(
    const unsigned short* __restrict__ A,
    const unsigned short* __restrict__ Bt,
    const float* __restrict__ b0,
    void* __restrict__ outp, int M, int N, int K) {
  __shared__ __align__(16) char lds[98304];
  gemm128x256_body<2, 1>(lds, (int)blockIdx.x, A, Bt, b0, outp, M, N, K);
}

// ---------------- flash attention (exact R13 body — measured best 68.3 us) ----------
__global__ __launch_bounds__(256, 4) void attn_kernel(
    const unsigned short* __restrict__ Q,
    const unsigned short* __restrict__ K,
    const unsigned short* __restrict__ Vt,
    unsigned short* __restrict__ Y) {
  __shared__ __align__(16) char Ks[2][8192];
  __shared__ __align__(16) char Vs[2][8192];

  const int tid = (int)threadIdx.x;
  const int w = tid >> 6, lane = tid & 63;
  const int l31 = lane & 31, hi = lane >> 5;

  const int n = (int)blockIdx.x;
  const int g = n & 255, k = n >> 8;
  const int bh = g >> 2;
  const int u = 2 * (g & 3) + (k >> 1);
  const int qt = (k & 1) ? (15 - u) : u;
  const int b = bh >> 4, h = bh & 15;

  const unsigned short* Qb = Q + (size_t)bh * TQ * HD;
  const char* Kb = (const char*)(K + (size_t)bh * TQ * HD);
  const char* Vb = (const char*)(Vt + (size_t)bh * HD * TQ);

  auto stage = [&](int buf, int kt) {
#pragma unroll
    for (int i = 0; i < 2; ++i) {
      const int s = i * 256 + tid;
      const int r32 = (s >> 8) * 32 + (s & 31);
      const int ck = ((s >> 6) & 3) * 32 + ((s >> 5) & 1) * 16;
      char* kdst = &Ks[buf][0] + i * 4096 + (w << 10);
      char* vdst = &Vs[buf][0] + i * 4096 + (w << 10);
      gload_lds16(Kb + (size_t)kt * 8192 + r32 * 128 + ck, kdst);
      gload_lds16(Vb + (size_t)r32 * 4096 + kt * 128 + ck, vdst);
    }
  };

  const int q0 = qt * 128 + w * 32;
  const int qg = q0 + l31;
  const int nkv = 2 * qt + 2;

  stage(0, 0);

  bf16x8 qf[4];
#pragma unroll
  for (int dk = 0; dk < 4; ++dk)
    qf[dk] = *(const bf16x8*)(Qb + (size_t)qg * HD + dk * 16 + hi * 8);

  f32x16 oac[2];
#pragma unroll
  for (int nb = 0; nb < 2; ++nb)
#pragma unroll
    for (int r = 0; r < 16; ++r) oac[nb][r] = 0.f;
  float mr = -3.0e38f, lr = 0.f;

  __syncthreads();

  for (int kt = 0; kt < nkv; ++kt) {
    const int cur = kt & 1;
    if (kt + 1 < nkv) stage(cur ^ 1, kt + 1);

    if (kt * 64 <= q0 + 31) {
      const char* Klane = &Ks[cur][0] + lane * 16;
      const char* Vlane = &Vs[cur][0] + lane * 16;

      f32x16 s0, s1;
#pragma unroll
      for (int r = 0; r < 16; ++r) { s0[r] = 0.f; s1[r] = 0.f; }
#pragma unroll
      for (int dk = 0; dk < 4; ++dk) {
        bf16x8 kf0 = *(const bf16x8*)(Klane + (dk << 10));
        bf16x8 kf1 = *(const bf16x8*)(Klane + ((4 + dk) << 10));
        s0 = __builtin_amdgcn_mfma_f32_32x32x16_bf16(kf0, qf[dk], s0, 0, 0, 0);
        s1 = __builtin_amdgcn_mfma_f32_32x32x16_bf16(kf1, qf[dk], s1, 0, 0, 0);
      }

      const bool maskT = (kt * 64 + 63 > q0);
      if (maskT) {
#pragma unroll
        for (int r = 0; r < 16; ++r) {
          int kv0 = kt * 64 + ((r & 3) + 8 * (r >> 2)) + 4 * hi;
          s0[r] = (kv0 <= qg) ? s0[r] : -3.0e38f;
          s1[r] = (kv0 + 32 <= qg) ? s1[r] : -3.0e38f;
        }
      }

      float mt_ = s0[0];
#pragma unroll
      for (int r = 1; r < 16; ++r) mt_ = fmaxf(mt_, s0[r]);
#pragma unroll
      for (int r = 0; r < 16; ++r) mt_ = fmaxf(mt_, s1[r]);
      mt_ = fmaxf(mt_, __shfl_xor(mt_, 32));

      if (!__all(mt_ - mr <= 8.0f)) {
        const float mn = fmaxf(mr, mt_);
        const float al = exp2_fast(mr - mn);
        mr = mn;
        lr *= al;
#pragma unroll
        for (int nb = 0; nb < 2; ++nb)
#pragma unroll
          for (int r = 0; r < 16; ++r) oac[nb][r] *= al;
      }

      float rs = 0.f;
#pragma unroll
      for (int r = 0; r < 16; ++r) { s0[r] = exp2_fast(s0[r] - mr); rs += s0[r]; }
#pragma unroll
      for (int r = 0; r < 16; ++r) { s1[r] = exp2_fast(s1[r] - mr); rs += s1[r]; }
      rs += __shfl_xor(rs, 32);
      lr += rs;

      bf16x8 pf[4];
      {
        unsigned a0 = cvtpk(s0[0], s0[1]), b0 = cvtpk(s0[2], s0[3]);
        unsigned c0 = cvtpk(s0[4], s0[5]), d0 = cvtpk(s0[6], s0[7]);
        plswap(a0, c0); plswap(b0, d0);
        unsigned a1 = cvtpk(s0[8], s0[9]), b1 = cvtpk(s0[10], s0[11]);
        unsigned c1 = cvtpk(s0[12], s0[13]), d1 = cvtpk(s0[14], s0[15]);
        plswap(a1, c1); plswap(b1, d1);
        unsigned a2 = cvtpk(s1[0], s1[1]), b2 = cvtpk(s1[2], s1[3]);
        unsigned c2 = cvtpk(s1[4], s1[5]), d2 = cvtpk(s1[6], s1[7]);
        plswap(a2, c2); plswap(b2, d2);
        unsigned a3 = cvtpk(s1[8], s1[9]), b3 = cvtpk(s1[10], s1[11]);
        unsigned c3 = cvtpk(s1[12], s1[13]), d3 = cvtpk(s1[14], s1[15]);
        plswap(a3, c3); plswap(b3, d3);
        union { unsigned u[4]; bf16x8 v; } t;
        t.u[0] = a0; t.u[1] = b0; t.u[2] = c0; t.u[3] = d0; pf[0] = t.v;
        t.u[0] = a1; t.u[1] = b1; t.u[2] = c1; t.u[3] = d1; pf[1] = t.v;
        t.u[0] = a2; t.u[1] = b2; t.u[2] = c2; t.u[3] = d2; pf[2] = t.v;
        t.u[0] = a3; t.u[1] = b3; t.u[2] = c3; t.u[3] = d3; pf[3] = t.v;
      }

#pragma unroll
      for (int nb = 0; nb < 2; ++nb)
#pragma unroll
        for (int ks = 0; ks < 4; ++ks) {
          bf16x8 vf = *(const bf16x8*)(Vlane + (((nb << 2) + ks) << 10));
          oac[nb] = __builtin_amdgcn_mfma_f32_32x32x16_bf16(vf, pf[ks], oac[nb], 0, 0, 0);
        }
    }
    __syncthreads();
  }

  float inv;
  asm("v_rcp_f32 %0, %1" : "=v"(inv) : "v"(lr));
  unsigned short* Yrow = Y + (size_t)(b * TQ + qg) * CDIM + h * 64;
#pragma unroll
  for (int nb = 0; nb < 2; ++nb)
#pragma unroll
    for (int j = 0; j < 8; ++j) {
      const int dbase = ((2 * j) & 3) + 8 * (j >> 1);
      unsigned lo = f2bf(oac[nb][2 * j] * inv);
      unsigned hi2 = f2bf(oac[nb][2 * j + 1] * inv);
      *(unsigned*)(Yrow + nb * 32 + dbase + 4 * hi) = lo | (hi2 << 16);
    }
}

// ---------------- launcher ----------------
extern "C" void kernel_launch(void* const* d_in, const int* in_sizes, int n_in,
                              void* d_out, int out_size, void* d_ws, size_t ws_size,
                              hipStream_t stream) {
  (void)in_sizes; (void)n_in; (void)out_size; (void)ws_size;
  const float* x  = (const float*)d_in[0];
  const float* Wq = (const float*)d_in[1];
  const float* bq = (const float*)d_in[2];
  const float* Wk = (const float*)d_in[3];
  const float* bk = (const float*)d_in[4];
  const float* Wv = (const float*)d_in[5];
  const float* bv = (const float*)d_in[6];
  const float* Wp = (const float*)d_in[7];
  const float* bp = (const float*)d_in[8];
  float* out = (float*)d_out;

  char* ws = (char*)d_ws;
  unsigned short* xb  = (unsigned short*)(ws + 0);
  unsigned short* wqb = (unsigned short*)(ws + 16777216);
  unsigned short* wvb = (unsigned short*)(ws + 20971520);
  unsigned short* wpb = (unsigned short*)(ws + 23068672);
  unsigned short* Qh  = (unsigned short*)(ws + 25165824);
  unsigned short* Kh  = (unsigned short*)(ws + 41943040);
  unsigned short* Vt  = (unsigned short*)(ws + 58720256);
  unsigned short* y   = (unsigned short*)(ws + 75497472);
  (void)Kh;

  cvt_all_kernel<<<8192, 256, 0, stream>>>(x, Wq, Wk, Wv, Wp, xb, wqb);

  // merged QK (blocks 0..255) + Vt (blocks 256..511): tail overlap, one less gap
  qkvt_kernel<<<512, 512, 0, stream>>>(xb, wqb, bq, bk, Qh, wvb, bv, Vt);

  attn_kernel<<<1024, 256, 0, stream>>>(Qh, Kh, Vt, y);

  proj_kernel<<<256, 512, 0, stream>>>(y, wpb, bp, out, 8192, 1024, 1024);
}